// Round 3
// baseline (112.003 us; speedup 1.0000x reference)
//
#include <hip/hip_runtime.h>

#define N 64
#define NPAD 65          // +1 pad: bank = (row+col)%32 -> 2-way alias only (free per m136)
#define ITERS 50
#define TEMP 12.5f
#define WEPS 1e-5f
#define QDIM 75
#define WDIM 5

__device__ __forceinline__ float waveReduceSum(float x) {
#pragma unroll
    for (int off = 32; off; off >>= 1) x += __shfl_xor(x, off, 64);
    return x;
}

// 1 wave/block; occupancy bounded by problem count (1500 waves / 1024 SIMDs),
// so let the allocator take ~512 VGPRs: Krow[64]+Kcol[64] MUST be resident.
__global__ __launch_bounds__(64, 1) void emd_sinkhorn_kernel(
    const float* __restrict__ sim,   // [B, 64, 64]
    const float* __restrict__ w1,    // [E, Q, W, N] == [B, N]
    const float* __restrict__ w2,    // [E, W, Q, N]  (transposed Q/W)
    float* __restrict__ out,         // [B]
    int B)
{
    __shared__ __align__(16) float S[N * NPAD];
    __shared__ __align__(16) float U[N];
    __shared__ __align__(16) float V[N];

    const int b    = blockIdx.x;
    const int lane = threadIdx.x;   // single wave per block
    const float* g = sim + (size_t)b * N * N;

    // ---- stage sim into padded LDS, coalesced float4 global loads ----
    const float4* g4 = (const float4*)g;
#pragma unroll
    for (int t = 0; t < 16; ++t) {
        float4 x = g4[t * 64 + lane];
        int idx = t * 64 + lane;
        int r = idx >> 4;           // = 4t + (lane>>4)
        int c = (idx & 15) * 4;     // = (lane&15)*4
        S[r * NPAD + c + 0] = x.x;
        S[r * NPAD + c + 1] = x.y;
        S[r * NPAD + c + 2] = x.z;
        S[r * NPAD + c + 3] = x.w;
    }
    __syncthreads();

    // ---- K row (lane = row) and K col (lane = col) in registers ----
    // K = exp(-cost/eps) = exp(20*(sim-1))
    float Krow[N], Kcol[N];
#pragma unroll
    for (int j = 0; j < N; ++j)
        Krow[j] = __expf((S[lane * NPAD + j] - 1.0f) * 20.0f);
#pragma unroll
    for (int i = 0; i < N; ++i)
        Kcol[i] = __expf((S[i * NPAD + lane] - 1.0f) * 20.0f);

    // PIN: volatile asm is opaque -> compiler cannot sink/rematerialize the
    // exp chains into the iteration loop; forces true VGPR residency.
#pragma unroll
    for (int j = 0; j < N; ++j) {
        asm volatile("" : "+v"(Krow[j]));
        asm volatile("" : "+v"(Kcol[j]));
    }

    // ---- marginals: relu + eps, renormalize to sum N ----
    float a = w1[(size_t)b * N + lane];
    a = fmaxf(a, 0.0f) + WEPS;
    a *= (float)N / waveReduceSum(a);

    const int e   = b / (QDIM * WDIM);
    const int rem = b % (QDIM * WDIM);
    const int q   = rem / WDIM;
    const int w   = rem % WDIM;
    float bb = w2[((((size_t)e * WDIM + w) * QDIM) + q) * N + lane];
    bb = fmaxf(bb, 0.0f) + WEPS;
    bb *= (float)N / waveReduceSum(bb);

    V[lane] = 1.0f;   // log_v = 0 init
    __syncthreads();

    float u = 0.0f;
#pragma unroll 1
    for (int it = 0; it < ITERS; ++it) {
        // u = a / (K v)  -- row matvec from registers, v broadcast from LDS
        const float4* V4 = (const float4*)V;
        float a0 = 0, a1 = 0, a2 = 0, a3 = 0, a4 = 0, a5 = 0, a6 = 0, a7 = 0;
#pragma unroll
        for (int j8 = 0; j8 < 8; ++j8) {
            float4 v0 = V4[2 * j8];
            float4 v1 = V4[2 * j8 + 1];
            a0 = fmaf(Krow[8 * j8 + 0], v0.x, a0);
            a1 = fmaf(Krow[8 * j8 + 1], v0.y, a1);
            a2 = fmaf(Krow[8 * j8 + 2], v0.z, a2);
            a3 = fmaf(Krow[8 * j8 + 3], v0.w, a3);
            a4 = fmaf(Krow[8 * j8 + 4], v1.x, a4);
            a5 = fmaf(Krow[8 * j8 + 5], v1.y, a5);
            a6 = fmaf(Krow[8 * j8 + 6], v1.z, a6);
            a7 = fmaf(Krow[8 * j8 + 7], v1.w, a7);
        }
        u = a * __builtin_amdgcn_rcpf(((a0 + a1) + (a2 + a3)) + ((a4 + a5) + (a6 + a7)));
        U[lane] = u;
        __syncthreads();

        // v = b / (K^T u) -- col matvec from registers, u broadcast from LDS
        const float4* U4 = (const float4*)U;
        a0 = 0; a1 = 0; a2 = 0; a3 = 0; a4 = 0; a5 = 0; a6 = 0; a7 = 0;
#pragma unroll
        for (int i8 = 0; i8 < 8; ++i8) {
            float4 u0 = U4[2 * i8];
            float4 u1 = U4[2 * i8 + 1];
            a0 = fmaf(Kcol[8 * i8 + 0], u0.x, a0);
            a1 = fmaf(Kcol[8 * i8 + 1], u0.y, a1);
            a2 = fmaf(Kcol[8 * i8 + 2], u0.z, a2);
            a3 = fmaf(Kcol[8 * i8 + 3], u0.w, a3);
            a4 = fmaf(Kcol[8 * i8 + 4], u1.x, a4);
            a5 = fmaf(Kcol[8 * i8 + 5], u1.y, a5);
            a6 = fmaf(Kcol[8 * i8 + 6], u1.z, a6);
            a7 = fmaf(Kcol[8 * i8 + 7], u1.w, a7);
        }
        float vv = bb * __builtin_amdgcn_rcpf(((a0 + a1) + (a2 + a3)) + ((a4 + a5) + (a6 + a7)));
        V[lane] = vv;
        __syncthreads();
    }

    // ---- score = sum_ij u_i K_ij v_j sim_ij ----
    float s0 = 0, s1 = 0, s2 = 0, s3 = 0;
#pragma unroll
    for (int j4 = 0; j4 < 16; ++j4) {
        float4 vv = ((const float4*)V)[j4];
        s0 = fmaf(Krow[4 * j4 + 0] * S[lane * NPAD + 4 * j4 + 0], vv.x, s0);
        s1 = fmaf(Krow[4 * j4 + 1] * S[lane * NPAD + 4 * j4 + 1], vv.y, s1);
        s2 = fmaf(Krow[4 * j4 + 2] * S[lane * NPAD + 4 * j4 + 2], vv.z, s2);
        s3 = fmaf(Krow[4 * j4 + 3] * S[lane * NPAD + 4 * j4 + 3], vv.w, s3);
    }
    float partial = u * ((s0 + s1) + (s2 + s3));
    float tot = waveReduceSum(partial);
    if (lane == 0) out[b] = tot * (TEMP / (float)N);
}

extern "C" void kernel_launch(void* const* d_in, const int* in_sizes, int n_in,
                              void* d_out, int out_size, void* d_ws, size_t ws_size,
                              hipStream_t stream) {
    const float* sim = (const float*)d_in[0];
    const float* w1  = (const float*)d_in[1];
    const float* w2  = (const float*)d_in[2];
    float* out       = (float*)d_out;
    const int B = in_sizes[0] / (N * N);   // 1500
    emd_sinkhorn_kernel<<<B, 64, 0, stream>>>(sim, w1, w2, out, B);
}

// Round 4
// 111.188 us; speedup vs baseline: 1.0073x; 1.0073x over previous
//
#include <hip/hip_runtime.h>

#define N 64
#define NPAD 65          // bank = (row+col)%32 -> conflict-free b32 row & col access
#define ITERS 50
#define TEMP 12.5f
#define WEPS 1e-5f
#define QDIM 75
#define WDIM 5

// broadcast lane j's value to all lanes via SGPR (VALU pipe, no LDS traffic)
__device__ __forceinline__ float rl(float x, int lane) {
    return __int_as_float(__builtin_amdgcn_readlane(__float_as_int(x), lane));
}

__device__ __forceinline__ float waveReduceSum(float x) {
#pragma unroll
    for (int off = 32; off; off >>= 1) x += __shfl_xor(x, off, 64);
    return x;
}

// 1 wave/block. Occupancy is problem-count-bound (1500 waves / 1024 SIMDs);
// let the allocator use the full unified VGPR/AGPR file for Krow/Kcol.
__global__ __launch_bounds__(64, 1) void emd_sinkhorn_kernel(
    const float* __restrict__ sim,   // [B, 64, 64]
    const float* __restrict__ w1,    // [E, Q, W, N] == [B, N]
    const float* __restrict__ w2,    // [E, W, Q, N]  (transposed Q/W)
    float* __restrict__ out,         // [B]
    int B)
{
    __shared__ float S[N * NPAD];    // sim matrix only; u/v never touch LDS

    const int b    = blockIdx.x;
    const int lane = threadIdx.x;    // single wave per block
    const float* g = sim + (size_t)b * N * N;

    // ---- stage sim into padded LDS, coalesced float4 global loads ----
    const float4* g4 = (const float4*)g;
#pragma unroll
    for (int t = 0; t < 16; ++t) {
        float4 x = g4[t * 64 + lane];
        int idx = t * 64 + lane;
        int r = idx >> 4;            // = element_offset/64
        int c = (idx & 15) * 4;
        S[r * NPAD + c + 0] = x.x;
        S[r * NPAD + c + 1] = x.y;
        S[r * NPAD + c + 2] = x.z;
        S[r * NPAD + c + 3] = x.w;
    }
    __syncthreads();

    // ---- K = exp(-cost/eps) = exp(20*(sim-1)); row i and col i per lane ----
    float Krow[N], Kcol[N];
#pragma unroll
    for (int j = 0; j < N; ++j)
        Krow[j] = __expf((S[lane * NPAD + j] - 1.0f) * 20.0f);
#pragma unroll
    for (int i = 0; i < N; ++i)
        Kcol[i] = __expf((S[i * NPAD + lane] - 1.0f) * 20.0f);

    // keep the exp chains out of the loop (opaque to sinking/remat)
#pragma unroll
    for (int j = 0; j < N; ++j) {
        asm volatile("" : "+v"(Krow[j]));
        asm volatile("" : "+v"(Kcol[j]));
    }

    // ---- marginals: relu + eps, renormalize to sum N ----
    float a = w1[(size_t)b * N + lane];
    a = fmaxf(a, 0.0f) + WEPS;
    a *= (float)N / waveReduceSum(a);

    const int e   = b / (QDIM * WDIM);
    const int rem = b % (QDIM * WDIM);
    const int q   = rem / WDIM;
    const int w   = rem % WDIM;
    float bb = w2[((((size_t)e * WDIM + w) * QDIM) + q) * N + lane];
    bb = fmaxf(bb, 0.0f) + WEPS;
    bb *= (float)N / waveReduceSum(bb);

    // ---- Sinkhorn: pure register/SGPR loop, zero LDS, zero barriers ----
    float v = 1.0f, u = 0.0f;
#pragma unroll 1
    for (int it = 0; it < ITERS; ++it) {
        // u = a / (K v):  v_j broadcast via readlane -> SGPR FMA operand
        float c0 = 0, c1 = 0, c2 = 0, c3 = 0, c4 = 0, c5 = 0, c6 = 0, c7 = 0;
#pragma unroll
        for (int j = 0; j < N; j += 8) {
            c0 = fmaf(Krow[j + 0], rl(v, j + 0), c0);
            c1 = fmaf(Krow[j + 1], rl(v, j + 1), c1);
            c2 = fmaf(Krow[j + 2], rl(v, j + 2), c2);
            c3 = fmaf(Krow[j + 3], rl(v, j + 3), c3);
            c4 = fmaf(Krow[j + 4], rl(v, j + 4), c4);
            c5 = fmaf(Krow[j + 5], rl(v, j + 5), c5);
            c6 = fmaf(Krow[j + 6], rl(v, j + 6), c6);
            c7 = fmaf(Krow[j + 7], rl(v, j + 7), c7);
        }
        u = a * __builtin_amdgcn_rcpf(((c0 + c1) + (c2 + c3)) + ((c4 + c5) + (c6 + c7)));

        // v = b / (K^T u):  u_i broadcast via readlane
        float d0 = 0, d1 = 0, d2 = 0, d3 = 0, d4 = 0, d5 = 0, d6 = 0, d7 = 0;
#pragma unroll
        for (int i = 0; i < N; i += 8) {
            d0 = fmaf(Kcol[i + 0], rl(u, i + 0), d0);
            d1 = fmaf(Kcol[i + 1], rl(u, i + 1), d1);
            d2 = fmaf(Kcol[i + 2], rl(u, i + 2), d2);
            d3 = fmaf(Kcol[i + 3], rl(u, i + 3), d3);
            d4 = fmaf(Kcol[i + 4], rl(u, i + 4), d4);
            d5 = fmaf(Kcol[i + 5], rl(u, i + 5), d5);
            d6 = fmaf(Kcol[i + 6], rl(u, i + 6), d6);
            d7 = fmaf(Kcol[i + 7], rl(u, i + 7), d7);
        }
        v = bb * __builtin_amdgcn_rcpf(((d0 + d1) + (d2 + d3)) + ((d4 + d5) + (d6 + d7)));
    }

    // ---- score = sum_ij u_i K_ij v_j sim_ij (S re-read from LDS, once) ----
    float s0 = 0, s1 = 0, s2 = 0, s3 = 0;
#pragma unroll
    for (int j = 0; j < N; j += 4) {
        s0 = fmaf(Krow[j + 0] * S[lane * NPAD + j + 0], rl(v, j + 0), s0);
        s1 = fmaf(Krow[j + 1] * S[lane * NPAD + j + 1], rl(v, j + 1), s1);
        s2 = fmaf(Krow[j + 2] * S[lane * NPAD + j + 2], rl(v, j + 2), s2);
        s3 = fmaf(Krow[j + 3] * S[lane * NPAD + j + 3], rl(v, j + 3), s3);
    }
    float partial = u * ((s0 + s1) + (s2 + s3));
    float tot = waveReduceSum(partial);
    if (lane == 0) out[b] = tot * (TEMP / (float)N);
}

extern "C" void kernel_launch(void* const* d_in, const int* in_sizes, int n_in,
                              void* d_out, int out_size, void* d_ws, size_t ws_size,
                              hipStream_t stream) {
    const float* sim = (const float*)d_in[0];
    const float* w1  = (const float*)d_in[1];
    const float* w2  = (const float*)d_in[2];
    float* out       = (float*)d_out;
    const int B = in_sizes[0] / (N * N);   // 1500
    emd_sinkhorn_kernel<<<B, 64, 0, stream>>>(sim, w1, w2, out, B);
}